// Round 3
// baseline (87.401 us; speedup 1.0000x reference)
//
#include <hip/hip_runtime.h>

#define B   16
#define C1  256          // channels per input
#define C2  512          // total channels after concat
#define HW  4096         // 64*64 pixels per channel
#define TAIL_PER_B 4     // tail blocks per batch (each covers 1024 pixels)

typedef float vf4 __attribute__((ext_vector_type(4)));   // nontemporal-capable

// ---------------------------------------------------------------------------
// Kernel 1: per-(batch, channel) global sum over H*W  -> pooled[B*C2]
// One WAVE per channel: 64 lanes x 16 float4 = 4096 floats. No LDS, no sync.
// 4 independent accumulators -> 16 loads in flight per lane.
// ---------------------------------------------------------------------------
__global__ __launch_bounds__(256) void pool_kernel(
    const float* __restrict__ x1, const float* __restrict__ x2,
    float* __restrict__ pooled)
{
    int t    = threadIdx.x;
    int wid  = t >> 6;              // wave 0..3
    int lane = t & 63;
    int bc   = blockIdx.x * 4 + wid;   // 0 .. B*C2-1  (grid = 512)
    int b    = bc >> 9;
    int c    = bc & (C2 - 1);
    const float* base = (c < C1)
        ? (x1 + (size_t)(b * C1 + c) * HW)
        : (x2 + (size_t)(b * C1 + (c - C1)) * HW);
    const vf4* p = (const vf4*)base;   // 1024 float4 per channel

    vf4 a0 = (vf4)(0.f), a1 = (vf4)(0.f), a2 = (vf4)(0.f), a3 = (vf4)(0.f);
    #pragma unroll
    for (int i = 0; i < 16; i += 4) {
        vf4 v0 = p[lane + (i + 0) * 64];
        vf4 v1 = p[lane + (i + 1) * 64];
        vf4 v2 = p[lane + (i + 2) * 64];
        vf4 v3 = p[lane + (i + 3) * 64];
        a0 += v0; a1 += v1; a2 += v2; a3 += v3;
    }
    vf4 a = (a0 + a1) + (a2 + a3);
    float s = (a.x + a.y) + (a.z + a.w);

    #pragma unroll
    for (int off = 32; off > 0; off >>= 1)
        s += __shfl_down(s, off, 64);

    if (lane == 0)
        pooled[bc] = s;
}

// ---------------------------------------------------------------------------
// Kernel 2: per-batch stable descending rank-sort of pooled values.
// idx[b*C2 + rank] = channel  (rank formula matches argsort(-pooled) stability)
// ---------------------------------------------------------------------------
__global__ __launch_bounds__(512) void sort_kernel(
    const float* __restrict__ pooled, int* __restrict__ idx)
{
    int b = blockIdx.x;
    int t = threadIdx.x;            // 512 threads = one per channel
    __shared__ float sp[C2];
    float v = pooled[b * C2 + t];
    sp[t] = v;
    __syncthreads();
    int rank = 0;
    for (int j = 0; j < C2; ++j) {
        float u = sp[j];
        rank += (u > v) || (u == v && j < t);
    }
    idx[b * C2 + rank] = t;
}

// ---------------------------------------------------------------------------
// Kernel 3: gather channels in sorted order; fold tail sum into channel k-1.
// Grid: [0, B*TAIL_PER_B)            -> tail blocks (channel k-1 + tail sum)
//       [B*TAIL_PER_B, +B*(k-1))     -> plain copy blocks (channels 0..k-2)
// Nontemporal stores: don't let the 64 MB streaming output evict the
// L3-resident inputs.
// ---------------------------------------------------------------------------
__global__ __launch_bounds__(256) void gather_kernel(
    const float* __restrict__ x1, const float* __restrict__ x2,
    const int* __restrict__ idx, float* __restrict__ out, int k)
{
    int t   = threadIdx.x;
    int bid = blockIdx.x;
    int ntail = B * TAIL_PER_B;
    __shared__ int ch[C2];          // tail channel list

    if (bid < ntail) {
        // ---- tail block: out[b, k-1, pix] = sum over channels idx[k-1..C2-1]
        int b     = bid / TAIL_PER_B;
        int chunk = bid % TAIL_PER_B;          // 1024 pixels per chunk
        int p4    = chunk * 256 + t;           // float4 index in channel
        int ntc   = C2 - k + 1;                // 257 channels to accumulate
        for (int i = t; i < ntc; i += 256)
            ch[i] = idx[b * C2 + (k - 1) + i];
        __syncthreads();

        vf4 acc0 = (vf4)(0.f), acc1 = (vf4)(0.f), acc2 = (vf4)(0.f), acc3 = (vf4)(0.f);
        const size_t boff = (size_t)b * C1 * HW;
        int i = 0;
        for (; i + 4 <= ntc; i += 4) {
            int c0 = ch[i], c1 = ch[i+1], c2 = ch[i+2], c3 = ch[i+3];
            const vf4* p0 = (const vf4*)((c0 < C1 ? x1 + boff + (size_t)c0*HW
                                                  : x2 + boff + (size_t)(c0-C1)*HW));
            const vf4* p1 = (const vf4*)((c1 < C1 ? x1 + boff + (size_t)c1*HW
                                                  : x2 + boff + (size_t)(c1-C1)*HW));
            const vf4* p2 = (const vf4*)((c2 < C1 ? x1 + boff + (size_t)c2*HW
                                                  : x2 + boff + (size_t)(c2-C1)*HW));
            const vf4* p3 = (const vf4*)((c3 < C1 ? x1 + boff + (size_t)c3*HW
                                                  : x2 + boff + (size_t)(c3-C1)*HW));
            acc0 += p0[p4]; acc1 += p1[p4]; acc2 += p2[p4]; acc3 += p3[p4];
        }
        for (; i < ntc; ++i) {
            int c0 = ch[i];
            const vf4* p0 = (const vf4*)((c0 < C1 ? x1 + boff + (size_t)c0*HW
                                                  : x2 + boff + (size_t)(c0-C1)*HW));
            acc0 += p0[p4];
        }
        vf4 acc = (acc0 + acc1) + (acc2 + acc3);
        vf4* o = (vf4*)(out + (size_t)(b * k + (k - 1)) * HW);
        __builtin_nontemporal_store(acc, o + p4);
    } else {
        // ---- plain copy block: out[b, o, :] = x[b, idx[b,o], :]
        int cb = bid - ntail;                  // 0 .. B*(k-1)-1
        int b  = cb / (k - 1);
        int o  = cb % (k - 1);
        int c  = idx[b * C2 + o];
        const vf4* src = (const vf4*)((c < C1)
            ? (x1 + (size_t)(b * C1 + c) * HW)
            : (x2 + (size_t)(b * C1 + (c - C1)) * HW));
        vf4* dst = (vf4*)(out + (size_t)(b * k + o) * HW);
        #pragma unroll
        for (int i = 0; i < 4; ++i)
            __builtin_nontemporal_store(src[t + i * 256], dst + t + i * 256);
    }
}

// ---------------------------------------------------------------------------
extern "C" void kernel_launch(void* const* d_in, const int* in_sizes, int n_in,
                              void* d_out, int out_size, void* d_ws, size_t ws_size,
                              hipStream_t stream)
{
    const float* x1 = (const float*)d_in[0];
    const float* x2 = (const float*)d_in[1];
    float* out = (float*)d_out;

    // k recovered from output size (deterministic, no device readback)
    int k = out_size / (B * HW);               // = 256

    float* pooled = (float*)d_ws;              // B*C2 floats = 32 KB
    int*   idx    = (int*)((char*)d_ws + B * C2 * sizeof(float)); // 32 KB

    pool_kernel<<<(B * C2) / 4, 256, 0, stream>>>(x1, x2, pooled);
    sort_kernel<<<B, 512, 0, stream>>>(pooled, idx);

    int ngather = B * TAIL_PER_B + B * (k - 1);
    gather_kernel<<<ngather, 256, 0, stream>>>(x1, x2, idx, out, k);
}